// Round 1
// baseline (803.119 us; speedup 1.0000x reference)
//
#include <hip/hip_runtime.h>

// MaxPool2d k=2 s=2 valid, NCHW fp32.
// In : (32, 96, 224, 224)  -> 154,140,672 floats
// Out: (32, 96, 112, 112)  ->  38,535,168 floats
//
// Pure streaming kernel: stride == kernel so each input element is read
// exactly once. One thread per output float4 (4 out cols = 8 in cols):
// 4x float4 loads (2 per input row) + 1x float4 store. 16B/lane coalesced.

#define IN_W   224
#define OUT_W  112
#define OUT_H  112
#define OUT_W4 (OUT_W / 4)   // 28 float4 per output row

__global__ __launch_bounds__(256) void maxpool2x2_kernel(
    const float* __restrict__ in, float* __restrict__ out, int n_out4) {
  int q = blockIdx.x * blockDim.x + threadIdx.x;
  if (q >= n_out4) return;

  // q -> (row_id, col4). row_id spans n*c*oh flattened (32*96*112 rows).
  int col4   = q % OUT_W4;
  int row_id = q / OUT_W4;
  int oh     = row_id % OUT_H;
  int nc     = row_id / OUT_H;

  // input base: nc planes of 224*224, row oh*2, col col4*8
  const float* p = in + (size_t)nc * (IN_W * IN_W) + (size_t)(oh * 2) * IN_W + col4 * 8;

  const float4* r0 = (const float4*)p;
  const float4* r1 = (const float4*)(p + IN_W);

  float4 a0 = r0[0];
  float4 a1 = r0[1];
  float4 b0 = r1[0];
  float4 b1 = r1[1];

  float4 o;
  o.x = fmaxf(fmaxf(a0.x, a0.y), fmaxf(b0.x, b0.y));
  o.y = fmaxf(fmaxf(a0.z, a0.w), fmaxf(b0.z, b0.w));
  o.z = fmaxf(fmaxf(a1.x, a1.y), fmaxf(b1.x, b1.y));
  o.w = fmaxf(fmaxf(a1.z, a1.w), fmaxf(b1.z, b1.w));

  ((float4*)out)[q] = o;
}

extern "C" void kernel_launch(void* const* d_in, const int* in_sizes, int n_in,
                              void* d_out, int out_size, void* d_ws, size_t ws_size,
                              hipStream_t stream) {
  const float* in = (const float*)d_in[0];
  float* out = (float*)d_out;
  int n_out4 = out_size / 4;  // 9,633,792 — divisible by 256 (37,632 blocks)
  int blocks = (n_out4 + 255) / 256;
  maxpool2x2_kernel<<<blocks, 256, 0, stream>>>(in, out, n_out4);
}

// Round 2
// 802.725 us; speedup vs baseline: 1.0005x; 1.0005x over previous
//
#include <hip/hip_runtime.h>

// MaxPool2d k=2 s=2 valid, NCHW fp32.
// In : (32, 96, 224, 224)  -> 154,140,672 floats
// Out: (32, 96, 112, 112)  ->  38,535,168 floats
//
// Streaming kernel (stride==kernel: each input byte read exactly once).
// One thread per output float2: 2 out cols = 4 in cols = one float4 per
// input row. Wave lanes are perfectly contiguous: 16 B/lane loads
// (1 KB/wave/instruction) and 8 B/lane stores. This fixes the previous
// version's 32 B lane stride (50% bytes-per-load-instruction efficiency
// through L1/TA).

#define IN_W   224
#define OUT_W  112
#define OUT_H  112
#define OUT_W2 (OUT_W / 2)   // 56 float2 per output row

__global__ __launch_bounds__(256) void maxpool2x2_kernel(
    const float* __restrict__ in, float* __restrict__ out, int n_out2) {
  int q = blockIdx.x * blockDim.x + threadIdx.x;
  if (q >= n_out2) return;

  // q -> (row_id, col2). row_id spans n*c*oh flattened (32*96*112 rows).
  int col2   = q % OUT_W2;
  int row_id = q / OUT_W2;
  int oh     = row_id % OUT_H;
  int nc     = row_id / OUT_H;

  const float* p = in + (size_t)nc * (IN_W * IN_W) + (size_t)(oh * 2) * IN_W + col2 * 4;

  float4 a = *(const float4*)p;           // input row 2*oh,   4 cols
  float4 b = *(const float4*)(p + IN_W);  // input row 2*oh+1, 4 cols

  float2 o;
  o.x = fmaxf(fmaxf(a.x, a.y), fmaxf(b.x, b.y));
  o.y = fmaxf(fmaxf(a.z, a.w), fmaxf(b.z, b.w));

  ((float2*)out)[q] = o;
}

extern "C" void kernel_launch(void* const* d_in, const int* in_sizes, int n_in,
                              void* d_out, int out_size, void* d_ws, size_t ws_size,
                              hipStream_t stream) {
  const float* in = (const float*)d_in[0];
  float* out = (float*)d_out;
  int n_out2 = out_size / 2;  // 19,267,584 — divisible by 256 (75,264 blocks)
  int blocks = (n_out2 + 255) / 256;
  maxpool2x2_kernel<<<blocks, 256, 0, stream>>>(in, out, n_out2);
}